// Round 6
// baseline (758.044 us; speedup 1.0000x reference)
//
#include <hip/hip_runtime.h>

#define NS   16384
#define NIN  16384
#define CIN  128
#define COUT 128
#define KNB  9
#define MCH  66              // 64 MLP channels + 1 (b3 ones) + 1 zero pad
#define QDIM (CIN*MCH)       // 8448, q = m*128 + j (j-fastest)
#define W0C  30.0f

typedef __bf16 bf16;
typedef bf16  bf16x8  __attribute__((ext_vector_type(8)));
typedef float floatx4 __attribute__((ext_vector_type(4)));
typedef unsigned int u32;

__device__ inline unsigned short f2bf(float f){
  u32 u = __float_as_uint(f);
  u += 0x7fffu + ((u >> 16) & 1u);   // round-to-nearest-even
  return (unsigned short)(u >> 16);
}
__device__ inline u32 pack2bf(float lo, float hi){
  return (u32)f2bf(lo) | ((u32)f2bf(hi) << 16);
}
__device__ inline float bf2f(unsigned short s){
  return __uint_as_float((u32)s << 16);
}

// ---------------- K0: Vt[i][q] bf16, q = m*128+j ----------------
__global__ void k0_vt(const float* __restrict__ W3, const float* __restrict__ b3,
                      unsigned short* __restrict__ Vt){
  int idx = blockIdx.x*256 + threadIdx.x;
  if (idx >= COUT*QDIM) return;
  int i = idx / QDIM;
  int q = idx - i*QDIM;
  int m = q >> 7;
  int j = q & 127;
  float v = 0.f;
  if (m < 64)       v = W3[m*16384 + i*128 + j];
  else if (m == 64) v = b3[i*128 + j];
  Vt[idx] = f2bf(v);
}

// ---------------- K1: SIREN MLP (fp32 math, bf16 out), h[pt][66] ----------------
__global__ __launch_bounds__(256) void k1_mlp(const float* __restrict__ coords,
      const float* __restrict__ W1, const float* __restrict__ b1,
      const float* __restrict__ W2, const float* __restrict__ b2,
      unsigned short* __restrict__ h){
  int lane = threadIdx.x & 63;
  int pt = blockIdx.x*4 + (threadIdx.x >> 6);
  float c0 = coords[2*pt], c1 = coords[2*pt+1];
  float z  = fmaf(c0, W1[lane], fmaf(c1, W1[64+lane], b1[lane]));
  float h1 = sinf(W0C * z);
  float acc = b2[lane];
  #pragma unroll
  for (int mp = 0; mp < 64; ++mp)
    acc = fmaf(__shfl(h1, mp, 64), W2[mp*64 + lane], acc);
  float h2 = sinf(acc);
  size_t base = (size_t)pt * MCH;
  h[base + lane] = f2bf(h2);
  if (lane == 0){ h[base+64] = 0x3F80; h[base+65] = 0; }  // 1.0, 0.0
}

// ---------------- K1tp: h[pt][66] -> hTp[g][pt] u32 (m-pair packed) ----------------
__global__ __launch_bounds__(256) void k1tp(const unsigned short* __restrict__ h,
                                            u32* __restrict__ hTp){
  __shared__ unsigned short t[128][68];
  int pt0 = blockIdx.x*128;
  int tid = threadIdx.x;
  for (int e = tid; e < 128*MCH; e += 256){
    int p = e / MCH, m = e - p*MCH;
    t[p][m] = h[(size_t)(pt0 + p)*MCH + m];
  }
  __syncthreads();
  for (int e = tid; e < 33*128; e += 256){
    int g = e >> 7, p = e & 127;
    hTp[(size_t)g*(KNB*NS) + pt0 + p] = (u32)t[p][2*g] | ((u32)t[p][2*g+1] << 16);
  }
}

// ---------------- K_tr: transpose x[b][j][p] -> xT[b][p][j] (bf16) ----------------
__global__ void k_tr(const float* __restrict__ x, unsigned short* __restrict__ xT){
  __shared__ __align__(16) float t[32][33];
  int b  = blockIdx.z;
  int j0 = blockIdx.y*32;
  int p0 = blockIdx.x*32;
  int tx = threadIdx.x, ty = threadIdx.y;
  const float*    xb  = x  + (size_t)b*CIN*NIN;
  unsigned short* xTb = xT + (size_t)b*NIN*CIN;
  #pragma unroll
  for (int n = 0; n < 4; ++n)
    t[ty+8*n][tx] = xb[(size_t)(j0+ty+8*n)*NIN + p0+tx];
  __syncthreads();
  #pragma unroll
  for (int n = 0; n < 4; ++n)
    xTb[(size_t)(p0+ty+8*n)*CIN + j0+tx] = f2bf(t[tx][ty+8*n]);
}

// ---------------- K_fused: reg gather + swizzled dbuf A + mm-split MFMA ------------
// block: 32 l (one b) x 128 i, 512 threads (8 waves).
// build identity: lq = tid>>4 (l), jc = tid&15 (j-chunk of 8).
// mfma identity:  wave w: nc = w&3 (i-group of 32), mm = w>>2 (m-half).
// A LDS: [buf][mm][row 32][256 B], chunk swizzle c ^= row&15. Double-buffered.
__global__ __launch_bounds__(512, 4) void k_fused(
      const unsigned short* __restrict__ xT,   // [4][16384][128] bf16
      const u32* __restrict__ hTp,             // [33][9*16384]   u32 (m-pair)
      const int* __restrict__ nb,              // [9][16384]
      const unsigned short* __restrict__ Vt,   // [128][8448]     bf16
      const float* __restrict__ bias,
      float* __restrict__ out){
  __shared__ __align__(16) char As[2*2*32*256];   // 32 KB
  __shared__ int pk[KNB][32];

  const int tid = threadIdx.x;
  const int r0  = blockIdx.x * 32;
  const int b   = r0 >> 14;
  const int l0  = r0 & (NS-1);

  if (tid < KNB*32)
    pk[tid >> 5][tid & 31] = nb[(tid >> 5)*NS + l0 + (tid & 31)];
  __syncthreads();

  const int lq = tid >> 4;      // 0..31
  const int jc = tid & 15;
  const char* xbB = (const char*)(xT + ((size_t)b << 21));
  bf16x8 xk[KNB];
  #pragma unroll
  for (int k = 0; k < KNB; ++k)
    xk[k] = *(const bf16x8*)(xbB + (((size_t)(u32)pk[k][lq]) << 8) + (size_t)jc*16);

  const int lane  = tid & 63;
  const int w     = tid >> 6;
  const int nc    = w & 3;      // i-group
  const int mm    = w >> 2;     // m-half
  const int ar    = lane & 15;
  const int klane = lane >> 4;

  // build write offset within a slab (row lq, swizzled chunk jc)
  const int woff = (lq << 8) + (((jc ^ (lq & 15))) << 4);

  u32 h[KNB];
  #pragma unroll
  for (int k = 0; k < KNB; ++k)
    h[k] = hTp[(size_t)0*(KNB*NS) + ((size_t)k << 14) + l0 + lq];

  // ---- build mg=0 into buf0 ----
  {
    float ax[8], ay[8];
    #pragma unroll
    for (int t = 0; t < 8; ++t){ ax[t] = 0.f; ay[t] = 0.f; }
    #pragma unroll
    for (int k = 0; k < KNB; ++k){
      float hk0 = bf2f((unsigned short)(h[k] & 0xffff));
      float hk1 = bf2f((unsigned short)(h[k] >> 16));
      #pragma unroll
      for (int t = 0; t < 8; ++t){
        float xf = (float)xk[k][t];
        ax[t] = fmaf(xf, hk0, ax[t]);
        ay[t] = fmaf(xf, hk1, ay[t]);
      }
    }
    u32 p0[4], p1[4];
    #pragma unroll
    for (int t = 0; t < 4; ++t){
      p0[t] = pack2bf(ax[2*t], ax[2*t+1]);
      p1[t] = pack2bf(ay[2*t], ay[2*t+1]);
    }
    *(uint4*)(As + woff)        = *(uint4*)p0;
    *(uint4*)(As + 8192 + woff) = *(uint4*)p1;
  }
  #pragma unroll
  for (int k = 0; k < KNB; ++k)
    h[k] = hTp[(size_t)1*(KNB*NS) + ((size_t)k << 14) + l0 + lq];
  __syncthreads();

  floatx4 acc[2][2];
  #pragma unroll
  for (int fr = 0; fr < 2; ++fr)
    #pragma unroll
    for (int fc = 0; fc < 2; ++fc) acc[fr][fc] = (floatx4){0.f,0.f,0.f,0.f};

  const char* Vw = (const char*)Vt + (size_t)(nc*32 + ar)*(QDIM*2) + (size_t)klane*16;
  const size_t VfcStep = (size_t)16*(QDIM*2);

  for (int mg = 0; mg <= 32; ++mg){
    const int cur = mg & 1;
    const char* Aslab = As + cur*16384 + mm*8192;
    const size_t qoff = (size_t)(mg*2 + mm)*256;
    #pragma unroll
    for (int kt = 0; kt < 4; ++kt){
      const int ch = (((kt*4 + klane) ^ ar)) << 4;
      bf16x8 av0 = *(const bf16x8*)(Aslab + (ar << 8) + ch);
      bf16x8 av1 = *(const bf16x8*)(Aslab + 4096 + (ar << 8) + ch);
      bf16x8 bv0 = *(const bf16x8*)(Vw + qoff + kt*64);
      bf16x8 bv1 = *(const bf16x8*)(Vw + VfcStep + qoff + kt*64);
      acc[0][0] = __builtin_amdgcn_mfma_f32_16x16x32_bf16(av0, bv0, acc[0][0], 0, 0, 0);
      acc[0][1] = __builtin_amdgcn_mfma_f32_16x16x32_bf16(av0, bv1, acc[0][1], 0, 0, 0);
      acc[1][0] = __builtin_amdgcn_mfma_f32_16x16x32_bf16(av1, bv0, acc[1][0], 0, 0, 0);
      acc[1][1] = __builtin_amdgcn_mfma_f32_16x16x32_bf16(av1, bv1, acc[1][1], 0, 0, 0);
    }
    if (mg < 32){
      // build mg+1 into other buffer (interleaves with this iter's MFMA)
      float ax[8], ay[8];
      #pragma unroll
      for (int t = 0; t < 8; ++t){ ax[t] = 0.f; ay[t] = 0.f; }
      #pragma unroll
      for (int k = 0; k < KNB; ++k){
        float hk0 = bf2f((unsigned short)(h[k] & 0xffff));
        float hk1 = bf2f((unsigned short)(h[k] >> 16));
        #pragma unroll
        for (int t = 0; t < 8; ++t){
          float xf = (float)xk[k][t];
          ax[t] = fmaf(xf, hk0, ax[t]);
          ay[t] = fmaf(xf, hk1, ay[t]);
        }
      }
      u32 p0[4], p1[4];
      #pragma unroll
      for (int t = 0; t < 4; ++t){
        p0[t] = pack2bf(ax[2*t], ax[2*t+1]);
        p1[t] = pack2bf(ay[2*t], ay[2*t+1]);
      }
      char* Anew = As + (cur^1)*16384;
      *(uint4*)(Anew + woff)        = *(uint4*)p0;
      *(uint4*)(Anew + 8192 + woff) = *(uint4*)p1;
      if (mg < 31){
        #pragma unroll
        for (int k = 0; k < KNB; ++k)
          h[k] = hTp[(size_t)(mg+2)*(KNB*NS) + ((size_t)k << 14) + l0 + lq];
      }
    }
    __syncthreads();
  }

  // ---- cross-wave reduce (mm halves) + epilogue ----
  float* red = (float*)As;   // 16 KB, safe: all MFMA reads drained by final barrier
  if (mm == 1){
    #pragma unroll
    for (int fr = 0; fr < 2; ++fr)
      #pragma unroll
      for (int fc = 0; fc < 2; ++fc){
        int ii = fc*16 + ar;
        #pragma unroll
        for (int rg = 0; rg < 4; ++rg){
          int li = fr*16 + klane*4 + rg;
          red[((nc << 5) + li)*32 + ii] = acc[fr][fc][rg];
        }
      }
  }
  __syncthreads();
  if (mm == 0){
    float* ob = out + ((size_t)b << 21);
    #pragma unroll
    for (int fc = 0; fc < 2; ++fc){
      int i = nc*32 + fc*16 + ar;
      float bi = bias[i];
      #pragma unroll
      for (int fr = 0; fr < 2; ++fr){
        int li = fr*16 + klane*4;
        float4 v;
        v.x = acc[fr][fc][0] + red[((nc<<5)+li+0)*32 + fc*16+ar] + bi;
        v.y = acc[fr][fc][1] + red[((nc<<5)+li+1)*32 + fc*16+ar] + bi;
        v.z = acc[fr][fc][2] + red[((nc<<5)+li+2)*32 + fc*16+ar] + bi;
        v.w = acc[fr][fc][3] + red[((nc<<5)+li+3)*32 + fc*16+ar] + bi;
        *(float4*)(ob + ((size_t)i << 14) + l0 + li) = v;
      }
    }
  }
}

// ---------------- Naive zero-workspace fallback (correctness net) ----------------
__global__ __launch_bounds__(256) void k_naive(const float* __restrict__ x,
      const int* __restrict__ nb, const float* __restrict__ coords,
      const float* __restrict__ W1, const float* __restrict__ b1,
      const float* __restrict__ W2, const float* __restrict__ b2,
      const float* __restrict__ W3, const float* __restrict__ b3,
      const float* __restrict__ bias, float* __restrict__ out){
  __shared__ __align__(16) float hk[KNB][68];
  __shared__ int pk[KNB];
  __shared__ __align__(16) float xg[4][KNB][128];
  __shared__ __align__(16) float ul[128][66];
  int tid = threadIdx.x;
  int l = blockIdx.x;
  int lane = tid & 63, wid = tid >> 6;
  if (tid < KNB) pk[tid] = nb[tid*NS + l];
  for (int k = wid; k < KNB; k += 4){
    int pt = k*NS + l;
    float c0 = coords[2*pt], c1 = coords[2*pt+1];
    float z  = fmaf(c0, W1[lane], fmaf(c1, W1[64+lane], b1[lane]));
    float h1 = sinf(W0C*z);
    float a = b2[lane];
    for (int mp = 0; mp < 64; ++mp)
      a = fmaf(__shfl(h1, mp, 64), W2[mp*64+lane], a);
    hk[k][lane] = sinf(a);
    if (lane == 0){ hk[k][64] = 1.f; hk[k][65] = 0.f; }
  }
  __syncthreads();
  for (int idx = tid; idx < 4*KNB*128; idx += 256){
    int b = idx / (KNB*128);
    int r = idx - b*KNB*128;
    int k = r >> 7;
    int j = r & 127;
    xg[b][k][j] = x[((size_t)b*CIN + j)*NIN + pk[k]];
  }
  __syncthreads();
  for (int b = 0; b < 4; ++b){
    for (int idx = tid; idx < 128*65; idx += 256){
      int j = idx / 65, m = idx - j*65;
      float s = 0.f;
      for (int k = 0; k < KNB; ++k) s = fmaf(xg[b][k][j], hk[k][m], s);
      ul[j][m] = s;
    }
    __syncthreads();
    if (tid < 128){
      int i = tid;
      float v = bias[i];
      for (int j = 0; j < 128; ++j){
        const float* wcol = W3 + i*128 + j;
        for (int m = 0; m < 64; ++m)
          v = fmaf(ul[j][m], wcol[(size_t)m*16384], v);
        v = fmaf(ul[j][64], b3[i*128+j], v);
      }
      out[((size_t)b<<21) + ((size_t)i<<14) + l] = v;
    }
    __syncthreads();
  }
}

extern "C" void kernel_launch(void* const* d_in, const int* in_sizes, int n_in,
                              void* d_out, int out_size, void* d_ws, size_t ws_size,
                              hipStream_t stream) {
  const float* x      = (const float*)d_in[0];
  const int*   nb     = (const int*)  d_in[1];
  const float* coords = (const float*)d_in[2];
  const float* W1     = (const float*)d_in[3];
  const float* b1     = (const float*)d_in[4];
  const float* W2     = (const float*)d_in[5];
  const float* b2     = (const float*)d_in[6];
  const float* W3     = (const float*)d_in[7];
  const float* b3     = (const float*)d_in[8];
  const float* bias   = (const float*)d_in[9];
  float* out = (float*)d_out;

  const size_t VT_BYTES = (size_t)COUT*QDIM*2;            //  2,162,688
  const size_t H_BYTES  = (size_t)KNB*NS*MCH*2;           // 19,464,192
  const size_t HT_BYTES = (size_t)33*KNB*NS*4;            // 19,464,192
  const size_t XT_BYTES = (size_t)4*NIN*CIN*2;            // 16,777,216
  const size_t FIXED    = VT_BYTES + H_BYTES + HT_BYTES + XT_BYTES;  // ~57.9 MB

  if (ws_size >= FIXED) {
    char* ws = (char*)d_ws;
    unsigned short* Vt = (unsigned short*)ws;
    unsigned short* h  = (unsigned short*)(ws + VT_BYTES);
    u32*            hTp= (u32*)(ws + VT_BYTES + H_BYTES);
    unsigned short* xT = (unsigned short*)(ws + VT_BYTES + H_BYTES + HT_BYTES);

    k0_vt<<<(COUT*QDIM + 255)/256, 256, 0, stream>>>(W3, b3, Vt);
    k1_mlp<<<(KNB*NS)/4, 256, 0, stream>>>(coords, W1, b1, W2, b2, h);
    k1tp<<<(KNB*NS)/128, 256, 0, stream>>>(h, hTp);
    k_tr<<<dim3(NIN/32, CIN/32, 4), dim3(32, 8), 0, stream>>>(x, xT);
    k_fused<<<(4*NS)/32, 512, 0, stream>>>(xT, hTp, nb, Vt, bias, out);
  } else {
    k_naive<<<NS, 256, 0, stream>>>(x, nb, coords, W1, b1, W2, b2, W3, b3, bias, out);
  }
  (void)in_sizes; (void)n_in; (void)out_size;
}